// Round 3
// baseline (437.460 us; speedup 1.0000x reference)
//
#include <hip/hip_runtime.h>
#include <cfloat>

// Shapes (fixed): x = [32, 1, 8192, 256] fp32 -> out = [32, 1, 4096, 256] fp32
// Strategy: two passes over the INPUT, never materializing the un-normalized
// pooled array. Pass A: read x, compute pooled values in registers, emit 1024
// per-block min/max partials (structural HBM: 256 MiB R). Pass B: reduce the
// 32 partials for this batch in a preamble, re-read x (hot in the 256 MiB L3
// after pass A), recompute pool, write normalized with non-temporal stores so
// the output stream doesn't evict the input from L3 (structural HBM: 128 MiB W
// + whatever input misses L3).
#define BATCH     32
#define H_IN      8192
#define H_OUT     4096
#define W4        64        // W=256 floats as float4
#define CH        32        // output rows per thread
#define BLK_PER_B 32        // blocks per batch (32 blocks * 4 waves * 32 rows = 4096)

typedef float vfloat4 __attribute__((ext_vector_type(4)));  // NT-store-compatible

__device__ __forceinline__ float4 max3_f4(float4 a, float4 b, float4 c) {
    float4 m;
    m.x = fmaxf(a.x, fmaxf(b.x, c.x));
    m.y = fmaxf(a.y, fmaxf(b.y, c.y));
    m.z = fmaxf(a.z, fmaxf(b.z, c.z));
    m.w = fmaxf(a.w, fmaxf(b.w, c.w));
    return m;
}

// Pass A: pooled min/max partials only — no pooled store. Grid: 1024 x 256.
__global__ __launch_bounds__(256) void pool_minmax(
        const float* __restrict__ x,
        float* __restrict__ partial_min, float* __restrict__ partial_max) {
    const int batch = blockIdx.x >> 5;
    const int blk   = blockIdx.x & 31;
    const int tid   = threadIdx.x;
    const int w4    = tid & 63;
    const int rg    = tid >> 6;                         // wave 0..3
    const int h0    = blk * 128 + rg * CH;              // first output row

    const float4* xin = (const float4*)x + (size_t)batch * H_IN * W4 + w4;

    float lmin = FLT_MAX, lmax = -FLT_MAX;

    float4 prev;
    const int r0 = 2 * h0 - 1;
    if (r0 >= 0) prev = xin[(size_t)r0 * W4];
    else         prev = make_float4(-FLT_MAX, -FLT_MAX, -FLT_MAX, -FLT_MAX);

    #pragma unroll 8
    for (int i = 0; i < CH; ++i) {
        const int r = 2 * (h0 + i);
        float4 a = xin[(size_t)r * W4];
        float4 c = xin[(size_t)(r + 1) * W4];
        float4 m = max3_f4(prev, a, c);
        prev = c;
        lmax = fmaxf(lmax, fmaxf(fmaxf(m.x, m.y), fmaxf(m.z, m.w)));
        lmin = fminf(lmin, fminf(fminf(m.x, m.y), fminf(m.z, m.w)));
    }

    #pragma unroll
    for (int off = 32; off > 0; off >>= 1) {
        lmax = fmaxf(lmax, __shfl_down(lmax, off, 64));
        lmin = fminf(lmin, __shfl_down(lmin, off, 64));
    }
    __shared__ float smax[4], smin[4];
    if ((tid & 63) == 0) { smax[rg] = lmax; smin[rg] = lmin; }
    __syncthreads();
    if (tid == 0) {
        float bmax = smax[0], bmin = smin[0];
        #pragma unroll
        for (int i = 1; i < 4; ++i) {
            bmax = fmaxf(bmax, smax[i]);
            bmin = fminf(bmin, smin[i]);
        }
        partial_max[blockIdx.x] = bmax;
        partial_min[blockIdx.x] = bmin;
    }
}

// Pass B: reduce partials in preamble, recompute pool, write normalized (NT).
// Grid: 1024 x 256.
__global__ __launch_bounds__(256) void pool_norm(
        const float* __restrict__ x,
        const float* __restrict__ partial_min, const float* __restrict__ partial_max,
        float* __restrict__ out) {
    const int batch = blockIdx.x >> 5;
    const int blk   = blockIdx.x & 31;
    const int tid   = threadIdx.x;
    const int w4    = tid & 63;
    const int rg    = tid >> 6;
    const int h0    = blk * 128 + rg * CH;

    __shared__ float s_mn, s_inv;
    if (tid < 64) {
        float mn = (tid < BLK_PER_B) ? partial_min[batch * BLK_PER_B + tid] : FLT_MAX;
        float mx = (tid < BLK_PER_B) ? partial_max[batch * BLK_PER_B + tid] : -FLT_MAX;
        #pragma unroll
        for (int off = 16; off > 0; off >>= 1) {
            mn = fminf(mn, __shfl_down(mn, off, 64));
            mx = fmaxf(mx, __shfl_down(mx, off, 64));
        }
        if (tid == 0) { s_mn = mn; s_inv = 1.0f / (mx - mn); }
    }
    __syncthreads();
    const float mn  = s_mn;
    const float inv = s_inv;

    const float4* xin = (const float4*)x + (size_t)batch * H_IN * W4 + w4;
    vfloat4*      po  = (vfloat4*)out + ((size_t)batch * H_OUT + h0) * W4 + w4;

    float4 prev;
    const int r0 = 2 * h0 - 1;
    if (r0 >= 0) prev = xin[(size_t)r0 * W4];
    else         prev = make_float4(-FLT_MAX, -FLT_MAX, -FLT_MAX, -FLT_MAX);

    #pragma unroll 8
    for (int i = 0; i < CH; ++i) {
        const int r = 2 * (h0 + i);
        float4 a = xin[(size_t)r * W4];
        float4 c = xin[(size_t)(r + 1) * W4];
        float4 m = max3_f4(prev, a, c);
        prev = c;
        vfloat4 v;
        v.x = (m.x - mn) * inv;
        v.y = (m.y - mn) * inv;
        v.z = (m.z - mn) * inv;
        v.w = (m.w - mn) * inv;
        __builtin_nontemporal_store(v, po + (size_t)i * W4);
    }
}

extern "C" void kernel_launch(void* const* d_in, const int* in_sizes, int n_in,
                              void* d_out, int out_size, void* d_ws, size_t ws_size,
                              hipStream_t stream) {
    const float* x   = (const float*)d_in[0];
    float*       out = (float*)d_out;
    float*       ws  = (float*)d_ws;

    float* pmin = ws;           // 1024 floats
    float* pmax = ws + 1024;    // 1024 floats

    pool_minmax<<<BATCH * BLK_PER_B, 256, 0, stream>>>(x, pmin, pmax);
    pool_norm<<<BATCH * BLK_PER_B, 256, 0, stream>>>(x, pmin, pmax, out);
}